// Round 1
// 1171.987 us; speedup vs baseline: 1.0258x; 1.0258x over previous
//
#include <hip/hip_runtime.h>
#include <hip/hip_bf16.h>

// Problem constants
constexpr int kB  = 16;
constexpr int kE  = 1024;
constexpr int kH  = 16;
constexpr int kN  = 2048;
constexpr int kEh = 64;
constexpr int kBH = 256;
constexpr int kM  = kN * kB;   // 32768 rows in the out-projection GEMM

typedef __bf16 bf16x8 __attribute__((ext_vector_type(8)));
typedef float  f32x4  __attribute__((ext_vector_type(4)));

static __device__ __forceinline__ unsigned short bf16_bits(float f) {
  union { __hip_bfloat16 h; unsigned short u; } cv;
  cv.h = __float2bfloat16(f);
  return cv.u;
}

// ---------------------------------------------------------------------------
// Kernel 1: in-projection. One block per output column j of in_proj_weight
// (j in [0, 3*E)). float4 loads: each thread owns 4 consecutive k's.
// ---------------------------------------------------------------------------
__global__ __launch_bounds__(256) void proj_kernel(
    const float* __restrict__ query, const float* __restrict__ key_in,
    const float* __restrict__ value, const float* __restrict__ W,
    const float* __restrict__ bias,
    float* __restrict__ q_step, float* __restrict__ k_step,
    float* __restrict__ v_step) {
  int j   = blockIdx.x;        // 0..3071
  int mat = j >> 10;           // 0=q,1=k,2=v
  int col = j & 1023;
  const float* in = (mat == 0) ? query : ((mat == 1) ? key_in : value);
  const float* wrow = W + (size_t)j * kE;
  int tid = threadIdx.x;

  float4 w4 = reinterpret_cast<const float4*>(wrow)[tid];
  float part[16];
#pragma unroll
  for (int r = 0; r < 16; ++r) {
    float4 in4 = reinterpret_cast<const float4*>(in + (size_t)r * kE)[tid];
    part[r] = w4.x * in4.x + w4.y * in4.y + w4.z * in4.z + w4.w * in4.w;
  }
  // wave reduce (lane 0 ends with the wave sum)
#pragma unroll
  for (int r = 0; r < 16; ++r) {
    float v = part[r];
    for (int off = 32; off > 0; off >>= 1) v += __shfl_down(v, off, 64);
    part[r] = v;
  }
  __shared__ float red[4][16];
  int wave = threadIdx.x >> 6;
  int lane = threadIdx.x & 63;
  if (lane == 0) {
#pragma unroll
    for (int r = 0; r < 16; ++r) red[wave][r] = part[r];
  }
  __syncthreads();
  if (threadIdx.x < 16) {
    int r = threadIdx.x;  // batch row
    float v = red[0][r] + red[1][r] + red[2][r] + red[3][r] + bias[j];
    int h = col >> 6, eh = col & 63;
    int bh = r * kH + h;
    if (mat == 0)      q_step[bh * kEh + eh] = v * 0.125f;  // 1/sqrt(64)
    else if (mat == 1) k_step[bh * kEh + eh] = v;
    else               v_step[bh * kEh + eh] = v;
  }
}

// ---------------------------------------------------------------------------
// Kernel 2: fp32 -> bf16 conversion of out_proj_weight
// ---------------------------------------------------------------------------
__global__ void wcvt_kernel(const float* __restrict__ w,
                            __hip_bfloat16* __restrict__ o, int n) {
  int i = blockIdx.x * blockDim.x + threadIdx.x;
  if (i < n) o[i] = __float2bfloat16(w[i]);
}

// ---------------------------------------------------------------------------
// Kernel 3: k_t pass, float4 along N. Each thread owns 4 dst columns
// c4..c4+3 (= src columns c4+1..c4+4). grid (kBH, 2), block 256.
// dst col 2047 gets a placeholder; final_kernel overwrites it.
// ---------------------------------------------------------------------------
__global__ __launch_bounds__(256) void kt_kernel(
    const float* __restrict__ k_t_mem, const float* __restrict__ q_step,
    float* __restrict__ k_t_out, float* __restrict__ a_tb1,
    float* __restrict__ top_sum) {
  int b = blockIdx.x;
  int chunk = blockIdx.y;  // 0..1
  __shared__ float qs[64];
  if (threadIdx.x < 64) qs[threadIdx.x] = q_step[b * kEh + threadIdx.x];
  __syncthreads();

  int c4 = (chunk * 256 + threadIdx.x) * 4;  // 0..2044, step 4
  bool last = (c4 + 4 >= kN);                // c4 == 2044
  const float* src = k_t_mem + (size_t)b * kEh * kN;
  float* dst = k_t_out + (size_t)b * kEh * kN;

  f32x4 dot = {0.f, 0.f, 0.f, 0.f};
#pragma unroll 4
  for (int e = 0; e < 64; ++e) {
    float4 a = reinterpret_cast<const float4*>(src + (size_t)e * kN)[c4 >> 2];
    float s3 = last ? 0.f : src[(size_t)e * kN + c4 + 4];
    float4 sh = {a.y, a.z, a.w, s3};
    reinterpret_cast<float4*>(dst + (size_t)e * kN)[c4 >> 2] = sh;
    float q = qs[e];
    dot.x += q * sh.x;
    dot.y += q * sh.y;
    dot.z += q * sh.z;
    dot.w += q * sh.w;
  }
  float tx = __expf(dot.x);
  float ty = __expf(dot.y);
  float tz = __expf(dot.z);
  float tw = last ? 0.f : __expf(dot.w);  // dst col 2047 is not a valid a_tb1 slot

  float* tbrow = a_tb1 + (size_t)b * (kN - 1);
  tbrow[c4 + 0] = tx;
  tbrow[c4 + 1] = ty;
  tbrow[c4 + 2] = tz;
  if (!last) tbrow[c4 + 3] = tw;

  float s = tx + ty + tz + tw;
  for (int off = 32; off > 0; off >>= 1) s += __shfl_xor(s, off, 64);
  __shared__ float red[4];
  int wave = threadIdx.x >> 6, lane = threadIdx.x & 63;
  if (lane == 0) red[wave] = s;
  __syncthreads();
  if (threadIdx.x == 0)
    atomicAdd(&top_sum[b], red[0] + red[1] + red[2] + red[3]);
}

// ---------------------------------------------------------------------------
// Kernel 4: q/av pass, 4 rows per wave. lane = (g,c): g=row-in-quad (lane>>4),
// c = 4-element group (lane&15). All loads/stores are float4 (16 B/lane);
// each row's two dot-reduces are 4 shfl_xor steps over 16 lanes.
// grid (kBH, 32), block 256: 4 waves x 4 quad-iters x 4 rows = 64 rows/block.
// ---------------------------------------------------------------------------
__global__ __launch_bounds__(256) void qav_kernel(
    const float* __restrict__ q_mem, const float* __restrict__ av_mem,
    const float* __restrict__ a_sum_mem, const float* __restrict__ k_t_mem,
    const float* __restrict__ v_mem, const float* __restrict__ k_step,
    const float* __restrict__ v_step, float* __restrict__ q_out,
    float* __restrict__ av_out, float* __restrict__ a_sum_out,
    __hip_bfloat16* __restrict__ attn) {
  int b = blockIdx.x;
  int chunk = blockIdx.y;  // 0..31
  int wave = threadIdx.x >> 6, lane = threadIdx.x & 63;
  int g = lane >> 4, c = lane & 15;
  int b_ = b >> 4, h = b & 15;

  float4 kst  = reinterpret_cast<const float4*>(k_step + (size_t)b * kEh)[c];
  float4 vst  = reinterpret_cast<const float4*>(v_step + (size_t)b * kEh)[c];
  float4 vold = reinterpret_cast<const float4*>(v_mem + (size_t)b * kN * kEh)[c];
  const float* kt0 = k_t_mem + (size_t)b * kEh * kN;
  float4 kold;
  kold.x = kt0[(size_t)(4 * c + 0) * kN];
  kold.y = kt0[(size_t)(4 * c + 1) * kN];
  kold.z = kt0[(size_t)(4 * c + 2) * kN];
  kold.w = kt0[(size_t)(4 * c + 3) * kN];

  unsigned short* attn_u = reinterpret_cast<unsigned short*>(attn);

  int jb = chunk * 64 + wave * 16;
#pragma unroll
  for (int it = 0; it < 4; ++it) {
    int j = jb + it * 4 + g;
    bool valid = (j <= kN - 2);        // only j==2047 masked
    int jc = valid ? j : (kN - 2);

    float4 q4 = reinterpret_cast<const float4*>(
        q_mem + ((size_t)b * kN + (jc + 1)) * kEh)[c];
    float p0 = q4.x * kold.x + q4.y * kold.y + q4.z * kold.z + q4.w * kold.w;
    float p1 = q4.x * kst.x + q4.y * kst.y + q4.z * kst.z + q4.w * kst.w;
#pragma unroll
    for (int off = 1; off < 16; off <<= 1) {
      p0 += __shfl_xor(p0, off, 64);
      p1 += __shfl_xor(p1, off, 64);
    }
    float a0 = __expf(p0);
    float a1 = __expf(p1);
    float asum = a_sum_mem[(size_t)b * (kN - 1) + jc] + a1 - a0;
    float4 av4 = reinterpret_cast<const float4*>(
        av_mem + ((size_t)b * (kN - 1) + jc) * kEh)[c];
    float4 avv;
    avv.x = av4.x - a0 * vold.x + a1 * vst.x;
    avv.y = av4.y - a0 * vold.y + a1 * vst.y;
    avv.z = av4.z - a0 * vold.z + a1 * vst.z;
    avv.w = av4.w - a0 * vold.w + a1 * vst.w;

    if (valid) {
      reinterpret_cast<float4*>(q_out + ((size_t)b * kN + jc) * kEh)[c] = q4;
      float inv = 1.0f / asum;
      ushort4 pk;
      pk.x = bf16_bits(avv.x * inv);
      pk.y = bf16_bits(avv.y * inv);
      pk.z = bf16_bits(avv.z * inv);
      pk.w = bf16_bits(avv.w * inv);
      *reinterpret_cast<ushort4*>(
          attn_u + ((size_t)jc * kB + b_) * kE + h * kEh + c * 4) = pk;
      if (j >= 1) {
        reinterpret_cast<float4*>(
            av_out + ((size_t)b * (kN - 1) + (jc - 1)) * kEh)[c] = avv;
        if (c == 0) a_sum_out[(size_t)b * (kN - 1) + (jc - 1)] = asum;
      }
    }
  }
}

// ---------------------------------------------------------------------------
// Kernel 5: v pass, 4 rows per wave iteration, float4 lanes.
// grid (kBH, 8), block 256: wave owns 64 rows (16 quad-iters).
// ---------------------------------------------------------------------------
__global__ __launch_bounds__(256) void v_kernel(
    const float* __restrict__ v_mem, const float* __restrict__ a_tb1,
    float* __restrict__ v_out, float* __restrict__ av_last) {
  int b = blockIdx.x;
  int chunk = blockIdx.y;  // 0..7
  int wave = threadIdx.x >> 6, lane = threadIdx.x & 63;
  int g = lane >> 4, c = lane & 15;
  const float* vsrc = v_mem + (size_t)b * kN * kEh;
  float* vdst = v_out + (size_t)b * kN * kEh;
  const float* tb = a_tb1 + (size_t)b * (kN - 1);

  f32x4 acc = {0.f, 0.f, 0.f, 0.f};
  int sbase = chunk * 256 + wave * 64;
#pragma unroll 4
  for (int it = 0; it < 16; ++it) {
    int s = sbase + it * 4 + g;
    bool valid = (s <= kN - 2);        // only s==2047 masked
    int sc = valid ? s : (kN - 2);
    float t = valid ? tb[sc] : 0.f;
    float4 vv = reinterpret_cast<const float4*>(vsrc + (size_t)(sc + 1) * kEh)[c];
    acc.x += t * vv.x;
    acc.y += t * vv.y;
    acc.z += t * vv.z;
    acc.w += t * vv.w;
    if (valid)
      reinterpret_cast<float4*>(vdst + (size_t)sc * kEh)[c] = vv;
  }
  // reduce across the 4 row-groups (lanes differing in bits 4,5)
#pragma unroll
  for (int off = 16; off <= 32; off <<= 1) {
    acc.x += __shfl_xor(acc.x, off, 64);
    acc.y += __shfl_xor(acc.y, off, 64);
    acc.z += __shfl_xor(acc.z, off, 64);
    acc.w += __shfl_xor(acc.w, off, 64);
  }
  __shared__ f32x4 red[4][16];
  if (g == 0) red[wave][c] = acc;
  __syncthreads();
  if (threadIdx.x < 16) {
    f32x4 a0 = red[0][threadIdx.x], a1 = red[1][threadIdx.x];
    f32x4 a2 = red[2][threadIdx.x], a3 = red[3][threadIdx.x];
    float* dst = av_last + (size_t)b * kEh + threadIdx.x * 4;
    atomicAdd(dst + 0, a0.x + a1.x + a2.x + a3.x);
    atomicAdd(dst + 1, a0.y + a1.y + a2.y + a3.y);
    atomicAdd(dst + 2, a0.z + a1.z + a2.z + a3.z);
    atomicAdd(dst + 3, a0.w + a1.w + a2.w + a3.w);
  }
}

// ---------------------------------------------------------------------------
// Kernel 6: finalize. Last row/column of all states + attn last row.
// grid kBH, block 64.
// ---------------------------------------------------------------------------
__global__ __launch_bounds__(64) void final_kernel(
    const float* __restrict__ q_step, const float* __restrict__ k_step,
    const float* __restrict__ v_step, const float* __restrict__ top_sum,
    const float* __restrict__ av_last_in, float* __restrict__ q_out,
    float* __restrict__ k_t_out, float* __restrict__ v_out,
    float* __restrict__ a_sum_out, float* __restrict__ av_out,
    __hip_bfloat16* __restrict__ attn) {
  int b = blockIdx.x;
  int lane = threadIdx.x;
  int b_ = b >> 4, h = b & 15;
  float qs = q_step[b * kEh + lane];
  float ks = k_step[b * kEh + lane];
  float vs = v_step[b * kEh + lane];
  float p = qs * ks;
  for (int off = 32; off > 0; off >>= 1) p += __shfl_xor(p, off, 64);
  float abr = __expf(p);
  float asum = top_sum[b] + abr;
  float avl = av_last_in[b * kEh + lane] + abr * vs;
  attn[((size_t)(kN - 1) * kB + b_) * kE + h * kEh + lane] =
      __float2bfloat16(avl / asum);
  if (lane == 0) a_sum_out[(size_t)b * (kN - 1) + (kN - 2)] = asum;
  av_out[((size_t)b * (kN - 1) + (kN - 2)) * kEh + lane] = avl;
  q_out[((size_t)b * kN + (kN - 1)) * kEh + lane] = qs;
  k_t_out[(size_t)b * kEh * kN + (size_t)lane * kN + (kN - 1)] = ks;
  v_out[((size_t)b * kN + (kN - 1)) * kEh + lane] = vs;
}

// ---------------------------------------------------------------------------
// Kernel 7: out-projection GEMM. C(M x 1024) = A(M x 1024 bf16) * W^T + bias.
// 128x128 tile, BK=64, 4 waves, 16x16x32 bf16 MFMA, global_load_lds width 16.
// ---------------------------------------------------------------------------
#define BM 128
#define BN 128
#define BK 64

__global__ __launch_bounds__(256) void gemm_kernel(
    const __bf16* __restrict__ A, const __bf16* __restrict__ Bw,
    const float* __restrict__ bias, float* __restrict__ C,
    int M, int Ncols, int K) {
  __shared__ __bf16 lA[BM * BK];  // 16 KB
  __shared__ __bf16 lB[BN * BK];  // 16 KB
  int tid = threadIdx.x;
  int m0 = blockIdx.x * BM;
  int n0 = blockIdx.y * BN;
  int wave = tid >> 6;
  int lane = tid & 63;
  int wm = (wave & 1) * 64;
  int wn = (wave >> 1) * 64;

  f32x4 zero = {0.f, 0.f, 0.f, 0.f};
  f32x4 acc[4][4];
#pragma unroll
  for (int i = 0; i < 4; ++i)
#pragma unroll
    for (int j = 0; j < 4; ++j) acc[i][j] = zero;

  int quad = lane >> 4;
  int mrow = lane & 15;

  for (int k0 = 0; k0 < K; k0 += BK) {
#pragma unroll
    for (int r = 0; r < 4; ++r) {
      int off = r * 4096 + tid * 16;  // byte offset inside tile
      int row = off >> 7;             // 0..127 (row = 128 B)
      int col8 = (off >> 4) & 7;      // 16B chunk within row
      const __bf16* ga = A + ((size_t)(m0 + row) * K + k0 + col8 * 8);
      const __bf16* gb = Bw + ((size_t)(n0 + row) * K + k0 + col8 * 8);
      __builtin_amdgcn_global_load_lds(
          (const __attribute__((address_space(1))) void*)ga,
          (__attribute__((address_space(3))) void*)((char*)lA + off), 16, 0, 0);
      __builtin_amdgcn_global_load_lds(
          (const __attribute__((address_space(1))) void*)gb,
          (__attribute__((address_space(3))) void*)((char*)lB + off), 16, 0, 0);
    }
    __syncthreads();

#pragma unroll
    for (int kk = 0; kk < 2; ++kk) {
      bf16x8 af[4], bfr[4];
#pragma unroll
      for (int i = 0; i < 4; ++i) {
        af[i]  = *(const bf16x8*)(&lA[(wm + i * 16 + mrow) * BK + kk * 32 + quad * 8]);
        bfr[i] = *(const bf16x8*)(&lB[(wn + i * 16 + mrow) * BK + kk * 32 + quad * 8]);
      }
#pragma unroll
      for (int i = 0; i < 4; ++i)
#pragma unroll
        for (int j = 0; j < 4; ++j)
          acc[i][j] = __builtin_amdgcn_mfma_f32_16x16x32_bf16(
              af[i], bfr[j], acc[i][j], 0, 0, 0);
    }
    __syncthreads();
  }

  // epilogue: C/D layout col=lane&15, row=(lane>>4)*4+reg
  int colq = lane & 15;
  int rowq = lane >> 4;
#pragma unroll
  for (int i = 0; i < 4; ++i) {
#pragma unroll
    for (int j = 0; j < 4; ++j) {
      int col = n0 + wn + j * 16 + colq;
      float bv = bias[col];
      size_t base = (size_t)(m0 + wm + i * 16 + rowq * 4) * Ncols + col;
#pragma unroll
      for (int r = 0; r < 4; ++r) {
        C[base + (size_t)r * Ncols] = acc[i][j][r] + bv;
      }
    }
  }
}

// ---------------------------------------------------------------------------
// Launch
// ---------------------------------------------------------------------------
extern "C" void kernel_launch(void* const* d_in, const int* in_sizes, int n_in,
                              void* d_out, int out_size, void* d_ws,
                              size_t ws_size, hipStream_t stream) {
  const float* query          = (const float*)d_in[0];
  const float* key_in         = (const float*)d_in[1];
  const float* value          = (const float*)d_in[2];
  const float* a_sum_mem      = (const float*)d_in[3];
  const float* av_mem         = (const float*)d_in[4];
  const float* q_mem          = (const float*)d_in[5];
  const float* k_t_mem        = (const float*)d_in[6];
  const float* v_mem          = (const float*)d_in[7];
  const float* in_proj_weight = (const float*)d_in[8];
  const float* in_proj_bias   = (const float*)d_in[9];
  const float* out_proj_weight= (const float*)d_in[10];
  const float* out_proj_bias  = (const float*)d_in[11];

  // Output layout (flat fp32, return order)
  float* out       = (float*)d_out;                          // N*B*E
  float* a_sum_out = out + (size_t)kN * kB * kE;             // BH*(N-1)
  float* av_out    = a_sum_out + (size_t)kBH * (kN - 1);     // BH*(N-1)*Eh
  float* q_out     = av_out + (size_t)kBH * (kN - 1) * kEh;  // BH*N*Eh
  float* k_t_out   = q_out + (size_t)kBH * kN * kEh;         // BH*Eh*N
  float* v_out     = k_t_out + (size_t)kBH * kEh * kN;       // BH*N*Eh

  // Workspace layout
  char* ws = (char*)d_ws;
  float* q_step  = (float*)ws;              // 16384 f
  float* k_step  = q_step + 16384;          // 16384 f
  float* v_step  = k_step + 16384;          // 16384 f
  float* top_sum = v_step + 16384;          // 256 f   (zeroed)
  float* av_last = top_sum + 256;           // 16384 f (zeroed)
  float* a_tb1   = av_last + 16384;         // 524032 f
  __hip_bfloat16* wo_bf   = (__hip_bfloat16*)(ws + 2359296);  // 1M bf16
  __hip_bfloat16* attn_bf = (__hip_bfloat16*)(ws + 4456448);  // 32M bf16

  // zero the atomic accumulators (top_sum + av_last = 16640 floats)
  hipMemsetAsync(ws + 196608, 0, 66560, stream);

  proj_kernel<<<3 * kE, 256, 0, stream>>>(query, key_in, value, in_proj_weight,
                                          in_proj_bias, q_step, k_step, v_step);
  wcvt_kernel<<<(kE * kE) / 256, 256, 0, stream>>>(out_proj_weight, wo_bf,
                                                   kE * kE);
  kt_kernel<<<dim3(kBH, 2), 256, 0, stream>>>(k_t_mem, q_step, k_t_out, a_tb1,
                                              top_sum);
  qav_kernel<<<dim3(kBH, 32), 256, 0, stream>>>(q_mem, av_mem, a_sum_mem,
                                                k_t_mem, v_mem, k_step, v_step,
                                                q_out, av_out, a_sum_out,
                                                attn_bf);
  v_kernel<<<dim3(kBH, 8), 256, 0, stream>>>(v_mem, a_tb1, v_out, av_last);
  final_kernel<<<kBH, 64, 0, stream>>>(q_step, k_step, v_step, top_sum,
                                       av_last, q_out, k_t_out, v_out,
                                       a_sum_out, av_out, attn_bf);
  gemm_kernel<<<dim3(kM / BM, kE / BN), 256, 0, stream>>>(
      (const __bf16*)attn_bf, (const __bf16*)wo_bf, out_proj_bias, out, kM, kE,
      kE);
}

// Round 2
// 1138.321 us; speedup vs baseline: 1.0561x; 1.0296x over previous
//
#include <hip/hip_runtime.h>
#include <hip/hip_bf16.h>

// Problem constants
constexpr int kB  = 16;
constexpr int kE  = 1024;
constexpr int kH  = 16;
constexpr int kN  = 2048;
constexpr int kEh = 64;
constexpr int kBH = 256;
constexpr int kM  = kN * kB;   // 32768 rows in the out-projection GEMM

typedef __bf16 bf16x8 __attribute__((ext_vector_type(8)));
typedef float  f32x4  __attribute__((ext_vector_type(4)));
typedef unsigned short u16x4 __attribute__((ext_vector_type(4)));

static __device__ __forceinline__ unsigned short bf16_bits(float f) {
  union { __hip_bfloat16 h; unsigned short u; } cv;
  cv.h = __float2bfloat16(f);
  return cv.u;
}

static __device__ __forceinline__ f32x4 nt_load4(const float* p) {
  return __builtin_nontemporal_load(reinterpret_cast<const f32x4*>(p));
}
static __device__ __forceinline__ void nt_store4(float* p, f32x4 v) {
  __builtin_nontemporal_store(v, reinterpret_cast<f32x4*>(p));
}

// ---------------------------------------------------------------------------
// Kernel 1: prep = in-projection (blocks 0..3071) + W_out fp32->bf16 cvt
// (blocks 3072..4095). Independent range-split paths.
// ---------------------------------------------------------------------------
__global__ __launch_bounds__(256) void prep_kernel(
    const float* __restrict__ query, const float* __restrict__ key_in,
    const float* __restrict__ value, const float* __restrict__ W,
    const float* __restrict__ bias,
    float* __restrict__ q_step, float* __restrict__ k_step,
    float* __restrict__ v_step,
    const float* __restrict__ wo, __hip_bfloat16* __restrict__ wo_bf) {
  __shared__ float red[4][16];
  int bid = blockIdx.x;
  int tid = threadIdx.x;
  if (bid >= 3072) {
    // ---- weight conversion: 1024 blocks x 256 threads x 4 elems ----
    int i4 = ((bid - 3072) * 256 + tid) * 4;
    f32x4 w4 = nt_load4(wo + i4);
    u16x4 o;
    o[0] = bf16_bits(w4[0]); o[1] = bf16_bits(w4[1]);
    o[2] = bf16_bits(w4[2]); o[3] = bf16_bits(w4[3]);
    *reinterpret_cast<u16x4*>(reinterpret_cast<unsigned short*>(wo_bf) + i4) = o;
    return;
  }
  // ---- in-projection ----
  int j   = bid;               // 0..3071
  int mat = j >> 10;           // 0=q,1=k,2=v
  int col = j & 1023;
  const float* in = (mat == 0) ? query : ((mat == 1) ? key_in : value);
  const float* wrow = W + (size_t)j * kE;

  float4 w4 = reinterpret_cast<const float4*>(wrow)[tid];
  float part[16];
#pragma unroll
  for (int r = 0; r < 16; ++r) {
    float4 in4 = reinterpret_cast<const float4*>(in + (size_t)r * kE)[tid];
    part[r] = w4.x * in4.x + w4.y * in4.y + w4.z * in4.z + w4.w * in4.w;
  }
#pragma unroll
  for (int r = 0; r < 16; ++r) {
    float v = part[r];
    for (int off = 32; off > 0; off >>= 1) v += __shfl_down(v, off, 64);
    part[r] = v;
  }
  int wave = tid >> 6;
  int lane = tid & 63;
  if (lane == 0) {
#pragma unroll
    for (int r = 0; r < 16; ++r) red[wave][r] = part[r];
  }
  __syncthreads();
  if (tid < 16) {
    int r = tid;  // batch row
    float v = red[0][r] + red[1][r] + red[2][r] + red[3][r] + bias[j];
    int h = col >> 6, eh = col & 63;
    int bh = r * kH + h;
    if (mat == 0)      q_step[bh * kEh + eh] = v * 0.125f;  // 1/sqrt(64)
    else if (mat == 1) k_step[bh * kEh + eh] = v;
    else               v_step[bh * kEh + eh] = v;
  }
}

// ---------------------------------------------------------------------------
// Kernel 2: stream = qav (blocks 0..8191) + fused kt/v (blocks 8192..8703).
//
// qav: 4 rows per wave, float4 lanes, 16-lane dot-reduce. (b=bid>>5, chunk=
// bid&31, 64 rows per block.)
//
// ktv: b = (bid-8192)>>1, chunk = (bid-8192)&1; 1024 columns per block.
//   phase 1: shift k_t along N, compute a_tb1 slice -> LDS tbuf + top_sum.
//   phase 2: shift v rows in the same index range, accumulate av_last with
//            tbuf weights (kt->v dependency is intra-block via barrier).
// ---------------------------------------------------------------------------
__global__ __launch_bounds__(256) void stream_kernel(
    const float* __restrict__ q_mem, const float* __restrict__ av_mem,
    const float* __restrict__ a_sum_mem, const float* __restrict__ k_t_mem,
    const float* __restrict__ v_mem, const float* __restrict__ q_step,
    const float* __restrict__ k_step, const float* __restrict__ v_step,
    float* __restrict__ q_out, float* __restrict__ av_out,
    float* __restrict__ a_sum_out, float* __restrict__ k_t_out,
    float* __restrict__ v_out, float* __restrict__ top_sum,
    float* __restrict__ av_last, __hip_bfloat16* __restrict__ attn) {
  __shared__ float qs[64];
  __shared__ float tbuf[1024];
  __shared__ f32x4 redv[4][16];
  __shared__ float redt[4];

  int bid = blockIdx.x;
  int tid = threadIdx.x;
  int wave = tid >> 6, lane = tid & 63;

  if (bid < 8192) {
    // ---------------- qav path ----------------
    int b = bid >> 5;
    int chunk = bid & 31;
    int g = lane >> 4, c = lane & 15;
    int b_ = b >> 4, h = b & 15;

    f32x4 kst  = *reinterpret_cast<const f32x4*>(k_step + (size_t)b * kEh + c * 4);
    f32x4 vst  = *reinterpret_cast<const f32x4*>(v_step + (size_t)b * kEh + c * 4);
    f32x4 vold = *reinterpret_cast<const f32x4*>(v_mem + (size_t)b * kN * kEh + c * 4);
    const float* kt0 = k_t_mem + (size_t)b * kEh * kN;
    f32x4 kold;
    kold[0] = kt0[(size_t)(4 * c + 0) * kN];
    kold[1] = kt0[(size_t)(4 * c + 1) * kN];
    kold[2] = kt0[(size_t)(4 * c + 2) * kN];
    kold[3] = kt0[(size_t)(4 * c + 3) * kN];

    unsigned short* attn_u = reinterpret_cast<unsigned short*>(attn);

    int jb = chunk * 64 + wave * 16;
#pragma unroll
    for (int it = 0; it < 4; ++it) {
      int j = jb + it * 4 + g;
      bool valid = (j <= kN - 2);        // only j==2047 masked
      int jc = valid ? j : (kN - 2);

      f32x4 q4 = nt_load4(q_mem + ((size_t)b * kN + (jc + 1)) * kEh + c * 4);
      float p0 = q4[0] * kold[0] + q4[1] * kold[1] + q4[2] * kold[2] + q4[3] * kold[3];
      float p1 = q4[0] * kst[0]  + q4[1] * kst[1]  + q4[2] * kst[2]  + q4[3] * kst[3];
#pragma unroll
      for (int off = 1; off < 16; off <<= 1) {
        p0 += __shfl_xor(p0, off, 64);
        p1 += __shfl_xor(p1, off, 64);
      }
      float a0 = __expf(p0);
      float a1 = __expf(p1);
      float asum = a_sum_mem[(size_t)b * (kN - 1) + jc] + a1 - a0;
      f32x4 av4 = nt_load4(av_mem + ((size_t)b * (kN - 1) + jc) * kEh + c * 4);
      f32x4 avv;
      avv[0] = av4[0] - a0 * vold[0] + a1 * vst[0];
      avv[1] = av4[1] - a0 * vold[1] + a1 * vst[1];
      avv[2] = av4[2] - a0 * vold[2] + a1 * vst[2];
      avv[3] = av4[3] - a0 * vold[3] + a1 * vst[3];

      if (valid) {
        nt_store4(q_out + ((size_t)b * kN + jc) * kEh + c * 4, q4);
        float inv = 1.0f / asum;
        u16x4 pk;
        pk[0] = bf16_bits(avv[0] * inv);
        pk[1] = bf16_bits(avv[1] * inv);
        pk[2] = bf16_bits(avv[2] * inv);
        pk[3] = bf16_bits(avv[3] * inv);
        *reinterpret_cast<u16x4*>(
            attn_u + ((size_t)jc * kB + b_) * kE + h * kEh + c * 4) = pk;
        if (j >= 1) {
          nt_store4(av_out + ((size_t)b * (kN - 1) + (jc - 1)) * kEh + c * 4, avv);
          if (c == 0) a_sum_out[(size_t)b * (kN - 1) + (jc - 1)] = asum;
        }
      }
    }
    return;
  }

  // ---------------- ktv path ----------------
  int id2 = bid - 8192;
  int b = id2 >> 1, chunk = id2 & 1;

  if (tid < 64) qs[tid] = q_step[b * kEh + tid];
  __syncthreads();

  // phase 1: k_t shift + a_tb1 slice
  int c4 = chunk * 1024 + tid * 4;      // 0..2044 step 4
  bool last = (c4 + 4 >= kN);           // c4 == 2044 (chunk 1, tid 255)
  const float* src = k_t_mem + (size_t)b * kEh * kN;
  float* dst = k_t_out + (size_t)b * kEh * kN;

  f32x4 dot = {0.f, 0.f, 0.f, 0.f};
#pragma unroll 4
  for (int e = 0; e < 64; ++e) {
    f32x4 a = nt_load4(src + (size_t)e * kN + c4);
    float s3 = last ? 0.f
                    : __builtin_nontemporal_load(src + (size_t)e * kN + c4 + 4);
    f32x4 sh;
    sh[0] = a[1]; sh[1] = a[2]; sh[2] = a[3]; sh[3] = s3;
    nt_store4(dst + (size_t)e * kN + c4, sh);
    float q = qs[e];
    dot[0] += q * sh[0];
    dot[1] += q * sh[1];
    dot[2] += q * sh[2];
    dot[3] += q * sh[3];
  }
  float tx = __expf(dot[0]);
  float ty = __expf(dot[1]);
  float tz = __expf(dot[2]);
  float tw = last ? 0.f : __expf(dot[3]);  // col 2047 is not a valid slot

  tbuf[tid * 4 + 0] = tx;
  tbuf[tid * 4 + 1] = ty;
  tbuf[tid * 4 + 2] = tz;
  tbuf[tid * 4 + 3] = tw;

  float s = tx + ty + tz + tw;
  for (int off = 32; off > 0; off >>= 1) s += __shfl_xor(s, off, 64);
  if (lane == 0) redt[wave] = s;
  __syncthreads();  // publishes tbuf + redt
  if (tid == 0)
    atomicAdd(&top_sum[b], redt[0] + redt[1] + redt[2] + redt[3]);

  // phase 2: v shift + av_last accumulate over the same index range
  int g = lane >> 4, c = lane & 15;
  const float* vsrc = v_mem + (size_t)b * kN * kEh;
  float* vdst = v_out + (size_t)b * kN * kEh;

  f32x4 acc = {0.f, 0.f, 0.f, 0.f};
  int sbase = chunk * 1024 + wave * 256;
#pragma unroll 4
  for (int it = 0; it < 64; ++it) {
    int s4 = sbase + it * 4 + g;
    bool valid = (s4 <= kN - 2);         // only s==2047 masked
    int sc = valid ? s4 : (kN - 2);
    float t = valid ? tbuf[s4 - chunk * 1024] : 0.f;
    f32x4 vv = nt_load4(vsrc + (size_t)(sc + 1) * kEh + c * 4);
    acc[0] += t * vv[0];
    acc[1] += t * vv[1];
    acc[2] += t * vv[2];
    acc[3] += t * vv[3];
    if (valid) nt_store4(vdst + (size_t)sc * kEh + c * 4, vv);
  }
#pragma unroll
  for (int off = 16; off <= 32; off <<= 1) {
    acc[0] += __shfl_xor(acc[0], off, 64);
    acc[1] += __shfl_xor(acc[1], off, 64);
    acc[2] += __shfl_xor(acc[2], off, 64);
    acc[3] += __shfl_xor(acc[3], off, 64);
  }
  if (g == 0) redv[wave][c] = acc;
  __syncthreads();
  if (tid < 16) {
    f32x4 a0 = redv[0][tid];
    f32x4 a1 = redv[1][tid];
    f32x4 a2 = redv[2][tid];
    f32x4 a3 = redv[3][tid];
    float* dstl = av_last + (size_t)b * kEh + tid * 4;
    atomicAdd(dstl + 0, a0[0] + a1[0] + a2[0] + a3[0]);
    atomicAdd(dstl + 1, a0[1] + a1[1] + a2[1] + a3[1]);
    atomicAdd(dstl + 2, a0[2] + a1[2] + a2[2] + a3[2]);
    atomicAdd(dstl + 3, a0[3] + a1[3] + a2[3] + a3[3]);
  }
}

// ---------------------------------------------------------------------------
// Kernel 3: finalize. Last row/column of all states + attn last row.
// grid kBH, block 64.
// ---------------------------------------------------------------------------
__global__ __launch_bounds__(64) void final_kernel(
    const float* __restrict__ q_step, const float* __restrict__ k_step,
    const float* __restrict__ v_step, const float* __restrict__ top_sum,
    const float* __restrict__ av_last_in, float* __restrict__ q_out,
    float* __restrict__ k_t_out, float* __restrict__ v_out,
    float* __restrict__ a_sum_out, float* __restrict__ av_out,
    __hip_bfloat16* __restrict__ attn) {
  int b = blockIdx.x;
  int lane = threadIdx.x;
  int b_ = b >> 4, h = b & 15;
  float qs = q_step[b * kEh + lane];
  float ks = k_step[b * kEh + lane];
  float vs = v_step[b * kEh + lane];
  float p = qs * ks;
  for (int off = 32; off > 0; off >>= 1) p += __shfl_xor(p, off, 64);
  float abr = __expf(p);
  float asum = top_sum[b] + abr;
  float avl = av_last_in[b * kEh + lane] + abr * vs;
  attn[((size_t)(kN - 1) * kB + b_) * kE + h * kEh + lane] =
      __float2bfloat16(avl / asum);
  if (lane == 0) a_sum_out[(size_t)b * (kN - 1) + (kN - 2)] = asum;
  av_out[((size_t)b * (kN - 1) + (kN - 2)) * kEh + lane] = avl;
  q_out[((size_t)b * kN + (kN - 1)) * kEh + lane] = qs;
  k_t_out[(size_t)b * kEh * kN + (size_t)lane * kN + (kN - 1)] = ks;
  v_out[((size_t)b * kN + (kN - 1)) * kEh + lane] = vs;
}

// ---------------------------------------------------------------------------
// Kernel 4: out-projection GEMM. C(M x 1024) = A(M x 1024 bf16) * W^T + bias.
// 128x128 tile, BK=64, 4 waves, 16x16x32 bf16 MFMA, global_load_lds width 16.
// NT stores on C (never re-read).
// ---------------------------------------------------------------------------
#define BM 128
#define BN 128
#define BK 64

__global__ __launch_bounds__(256) void gemm_kernel(
    const __bf16* __restrict__ A, const __bf16* __restrict__ Bw,
    const float* __restrict__ bias, float* __restrict__ C,
    int M, int Ncols, int K) {
  __shared__ __bf16 lA[BM * BK];  // 16 KB
  __shared__ __bf16 lB[BN * BK];  // 16 KB
  int tid = threadIdx.x;
  int m0 = blockIdx.x * BM;
  int n0 = blockIdx.y * BN;
  int wave = tid >> 6;
  int lane = tid & 63;
  int wm = (wave & 1) * 64;
  int wn = (wave >> 1) * 64;

  f32x4 zero = {0.f, 0.f, 0.f, 0.f};
  f32x4 acc[4][4];
#pragma unroll
  for (int i = 0; i < 4; ++i)
#pragma unroll
    for (int j = 0; j < 4; ++j) acc[i][j] = zero;

  int quad = lane >> 4;
  int mrow = lane & 15;

  for (int k0 = 0; k0 < K; k0 += BK) {
#pragma unroll
    for (int r = 0; r < 4; ++r) {
      int off = r * 4096 + tid * 16;  // byte offset inside tile
      int row = off >> 7;             // 0..127 (row = 128 B)
      int col8 = (off >> 4) & 7;      // 16B chunk within row
      const __bf16* ga = A + ((size_t)(m0 + row) * K + k0 + col8 * 8);
      const __bf16* gb = Bw + ((size_t)(n0 + row) * K + k0 + col8 * 8);
      __builtin_amdgcn_global_load_lds(
          (const __attribute__((address_space(1))) void*)ga,
          (__attribute__((address_space(3))) void*)((char*)lA + off), 16, 0, 0);
      __builtin_amdgcn_global_load_lds(
          (const __attribute__((address_space(1))) void*)gb,
          (__attribute__((address_space(3))) void*)((char*)lB + off), 16, 0, 0);
    }
    __syncthreads();

#pragma unroll
    for (int kk = 0; kk < 2; ++kk) {
      bf16x8 af[4], bfr[4];
#pragma unroll
      for (int i = 0; i < 4; ++i) {
        af[i]  = *(const bf16x8*)(&lA[(wm + i * 16 + mrow) * BK + kk * 32 + quad * 8]);
        bfr[i] = *(const bf16x8*)(&lB[(wn + i * 16 + mrow) * BK + kk * 32 + quad * 8]);
      }
#pragma unroll
      for (int i = 0; i < 4; ++i)
#pragma unroll
        for (int j = 0; j < 4; ++j)
          acc[i][j] = __builtin_amdgcn_mfma_f32_16x16x32_bf16(
              af[i], bfr[j], acc[i][j], 0, 0, 0);
    }
    __syncthreads();
  }

  // epilogue: C/D layout col=lane&15, row=(lane>>4)*4+reg
  int colq = lane & 15;
  int rowq = lane >> 4;
#pragma unroll
  for (int i = 0; i < 4; ++i) {
#pragma unroll
    for (int j = 0; j < 4; ++j) {
      int col = n0 + wn + j * 16 + colq;
      float bv = bias[col];
      size_t base = (size_t)(m0 + wm + i * 16 + rowq * 4) * Ncols + col;
#pragma unroll
      for (int r = 0; r < 4; ++r) {
        __builtin_nontemporal_store(acc[i][j][r] + bv,
                                    &C[base + (size_t)r * Ncols]);
      }
    }
  }
}

// ---------------------------------------------------------------------------
// Launch
// ---------------------------------------------------------------------------
extern "C" void kernel_launch(void* const* d_in, const int* in_sizes, int n_in,
                              void* d_out, int out_size, void* d_ws,
                              size_t ws_size, hipStream_t stream) {
  const float* query          = (const float*)d_in[0];
  const float* key_in         = (const float*)d_in[1];
  const float* value          = (const float*)d_in[2];
  const float* a_sum_mem      = (const float*)d_in[3];
  const float* av_mem         = (const float*)d_in[4];
  const float* q_mem          = (const float*)d_in[5];
  const float* k_t_mem        = (const float*)d_in[6];
  const float* v_mem          = (const float*)d_in[7];
  const float* in_proj_weight = (const float*)d_in[8];
  const float* in_proj_bias   = (const float*)d_in[9];
  const float* out_proj_weight= (const float*)d_in[10];
  const float* out_proj_bias  = (const float*)d_in[11];

  // Output layout (flat fp32, return order)
  float* out       = (float*)d_out;                          // N*B*E
  float* a_sum_out = out + (size_t)kN * kB * kE;             // BH*(N-1)
  float* av_out    = a_sum_out + (size_t)kBH * (kN - 1);     // BH*(N-1)*Eh
  float* q_out     = av_out + (size_t)kBH * (kN - 1) * kEh;  // BH*N*Eh
  float* k_t_out   = q_out + (size_t)kBH * kN * kEh;         // BH*Eh*N
  float* v_out     = k_t_out + (size_t)kBH * kEh * kN;       // BH*N*Eh

  // Workspace layout
  char* ws = (char*)d_ws;
  float* q_step  = (float*)ws;              // 16384 f
  float* k_step  = q_step + 16384;          // 16384 f
  float* v_step  = k_step + 16384;          // 16384 f
  float* top_sum = v_step + 16384;          // 256 f   (zeroed)
  float* av_last = top_sum + 256;           // 16384 f (zeroed)
  __hip_bfloat16* wo_bf   = (__hip_bfloat16*)(ws + 2359296);  // 1M bf16
  __hip_bfloat16* attn_bf = (__hip_bfloat16*)(ws + 4456448);  // 32M bf16

  // zero the atomic accumulators (top_sum + av_last = 16640 floats)
  hipMemsetAsync(ws + 196608, 0, 66560, stream);

  prep_kernel<<<4096, 256, 0, stream>>>(query, key_in, value, in_proj_weight,
                                        in_proj_bias, q_step, k_step, v_step,
                                        out_proj_weight, wo_bf);
  stream_kernel<<<8704, 256, 0, stream>>>(q_mem, av_mem, a_sum_mem, k_t_mem,
                                          v_mem, q_step, k_step, v_step, q_out,
                                          av_out, a_sum_out, k_t_out, v_out,
                                          top_sum, av_last, attn_bf);
  final_kernel<<<kBH, 64, 0, stream>>>(q_step, k_step, v_step, top_sum,
                                       av_last, q_out, k_t_out, v_out,
                                       a_sum_out, av_out, attn_bf);
  gemm_kernel<<<dim3(kM / BM, kE / BN), 256, 0, stream>>>(
      (const __bf16*)attn_bf, (const __bf16*)wo_bf, out_proj_bias, out, kM, kE,
      kE);
}

// Round 3
// 1114.239 us; speedup vs baseline: 1.0790x; 1.0216x over previous
//
#include <hip/hip_runtime.h>
#include <hip/hip_bf16.h>

// Problem constants
constexpr int kB  = 16;
constexpr int kE  = 1024;
constexpr int kH  = 16;
constexpr int kN  = 2048;
constexpr int kEh = 64;
constexpr int kBH = 256;
constexpr int kM  = kN * kB;   // 32768 rows in the out-projection GEMM

typedef __bf16 bf16x8 __attribute__((ext_vector_type(8)));
typedef float  f32x4  __attribute__((ext_vector_type(4)));
typedef unsigned short u16x4 __attribute__((ext_vector_type(4)));

static __device__ __forceinline__ unsigned short bf16_bits(float f) {
  union { __hip_bfloat16 h; unsigned short u; } cv;
  cv.h = __float2bfloat16(f);
  return cv.u;
}

static __device__ __forceinline__ f32x4 nt_load4(const float* p) {
  return __builtin_nontemporal_load(reinterpret_cast<const f32x4*>(p));
}
static __device__ __forceinline__ void nt_store4(float* p, f32x4 v) {
  __builtin_nontemporal_store(v, reinterpret_cast<f32x4*>(p));
}

// ---------------------------------------------------------------------------
// Kernel 1: prep = in-projection (blocks 0..3071) + W_out fp32->bf16 cvt
// (blocks 3072..4095). Independent range-split paths.
// ---------------------------------------------------------------------------
__global__ __launch_bounds__(256) void prep_kernel(
    const float* __restrict__ query, const float* __restrict__ key_in,
    const float* __restrict__ value, const float* __restrict__ W,
    const float* __restrict__ bias,
    float* __restrict__ q_step, float* __restrict__ k_step,
    float* __restrict__ v_step,
    const float* __restrict__ wo, __hip_bfloat16* __restrict__ wo_bf) {
  __shared__ float red[4][16];
  int bid = blockIdx.x;
  int tid = threadIdx.x;
  if (bid >= 3072) {
    // ---- weight conversion: 1024 blocks x 256 threads x 4 elems ----
    int i4 = ((bid - 3072) * 256 + tid) * 4;
    f32x4 w4 = nt_load4(wo + i4);
    u16x4 o;
    o[0] = bf16_bits(w4[0]); o[1] = bf16_bits(w4[1]);
    o[2] = bf16_bits(w4[2]); o[3] = bf16_bits(w4[3]);
    *reinterpret_cast<u16x4*>(reinterpret_cast<unsigned short*>(wo_bf) + i4) = o;
    return;
  }
  // ---- in-projection ----
  int j   = bid;               // 0..3071
  int mat = j >> 10;           // 0=q,1=k,2=v
  int col = j & 1023;
  const float* in = (mat == 0) ? query : ((mat == 1) ? key_in : value);
  const float* wrow = W + (size_t)j * kE;

  float4 w4 = reinterpret_cast<const float4*>(wrow)[tid];
  float part[16];
#pragma unroll
  for (int r = 0; r < 16; ++r) {
    float4 in4 = reinterpret_cast<const float4*>(in + (size_t)r * kE)[tid];
    part[r] = w4.x * in4.x + w4.y * in4.y + w4.z * in4.z + w4.w * in4.w;
  }
#pragma unroll
  for (int r = 0; r < 16; ++r) {
    float v = part[r];
    for (int off = 32; off > 0; off >>= 1) v += __shfl_down(v, off, 64);
    part[r] = v;
  }
  int wave = tid >> 6;
  int lane = tid & 63;
  if (lane == 0) {
#pragma unroll
    for (int r = 0; r < 16; ++r) red[wave][r] = part[r];
  }
  __syncthreads();
  if (tid < 16) {
    int r = tid;  // batch row
    float v = red[0][r] + red[1][r] + red[2][r] + red[3][r] + bias[j];
    int h = col >> 6, eh = col & 63;
    int bh = r * kH + h;
    if (mat == 0)      q_step[bh * kEh + eh] = v * 0.125f;  // 1/sqrt(64)
    else if (mat == 1) k_step[bh * kEh + eh] = v;
    else               v_step[bh * kEh + eh] = v;
  }
}

// ---------------------------------------------------------------------------
// Kernel 2: stream = qav (blocks 0..8191) + fused kt/v (blocks 8192..8703).
// (unchanged from verified R2 version)
// ---------------------------------------------------------------------------
__global__ __launch_bounds__(256) void stream_kernel(
    const float* __restrict__ q_mem, const float* __restrict__ av_mem,
    const float* __restrict__ a_sum_mem, const float* __restrict__ k_t_mem,
    const float* __restrict__ v_mem, const float* __restrict__ q_step,
    const float* __restrict__ k_step, const float* __restrict__ v_step,
    float* __restrict__ q_out, float* __restrict__ av_out,
    float* __restrict__ a_sum_out, float* __restrict__ k_t_out,
    float* __restrict__ v_out, float* __restrict__ top_sum,
    float* __restrict__ av_last, __hip_bfloat16* __restrict__ attn) {
  __shared__ float qs[64];
  __shared__ float tbuf[1024];
  __shared__ f32x4 redv[4][16];
  __shared__ float redt[4];

  int bid = blockIdx.x;
  int tid = threadIdx.x;
  int wave = tid >> 6, lane = tid & 63;

  if (bid < 8192) {
    // ---------------- qav path ----------------
    int b = bid >> 5;
    int chunk = bid & 31;
    int g = lane >> 4, c = lane & 15;
    int b_ = b >> 4, h = b & 15;

    f32x4 kst  = *reinterpret_cast<const f32x4*>(k_step + (size_t)b * kEh + c * 4);
    f32x4 vst  = *reinterpret_cast<const f32x4*>(v_step + (size_t)b * kEh + c * 4);
    f32x4 vold = *reinterpret_cast<const f32x4*>(v_mem + (size_t)b * kN * kEh + c * 4);
    const float* kt0 = k_t_mem + (size_t)b * kEh * kN;
    f32x4 kold;
    kold[0] = kt0[(size_t)(4 * c + 0) * kN];
    kold[1] = kt0[(size_t)(4 * c + 1) * kN];
    kold[2] = kt0[(size_t)(4 * c + 2) * kN];
    kold[3] = kt0[(size_t)(4 * c + 3) * kN];

    unsigned short* attn_u = reinterpret_cast<unsigned short*>(attn);

    int jb = chunk * 64 + wave * 16;
#pragma unroll
    for (int it = 0; it < 4; ++it) {
      int j = jb + it * 4 + g;
      bool valid = (j <= kN - 2);        // only j==2047 masked
      int jc = valid ? j : (kN - 2);

      f32x4 q4 = nt_load4(q_mem + ((size_t)b * kN + (jc + 1)) * kEh + c * 4);
      float p0 = q4[0] * kold[0] + q4[1] * kold[1] + q4[2] * kold[2] + q4[3] * kold[3];
      float p1 = q4[0] * kst[0]  + q4[1] * kst[1]  + q4[2] * kst[2]  + q4[3] * kst[3];
#pragma unroll
      for (int off = 1; off < 16; off <<= 1) {
        p0 += __shfl_xor(p0, off, 64);
        p1 += __shfl_xor(p1, off, 64);
      }
      float a0 = __expf(p0);
      float a1 = __expf(p1);
      float asum = a_sum_mem[(size_t)b * (kN - 1) + jc] + a1 - a0;
      f32x4 av4 = nt_load4(av_mem + ((size_t)b * (kN - 1) + jc) * kEh + c * 4);
      f32x4 avv;
      avv[0] = av4[0] - a0 * vold[0] + a1 * vst[0];
      avv[1] = av4[1] - a0 * vold[1] + a1 * vst[1];
      avv[2] = av4[2] - a0 * vold[2] + a1 * vst[2];
      avv[3] = av4[3] - a0 * vold[3] + a1 * vst[3];

      if (valid) {
        nt_store4(q_out + ((size_t)b * kN + jc) * kEh + c * 4, q4);
        float inv = 1.0f / asum;
        u16x4 pk;
        pk[0] = bf16_bits(avv[0] * inv);
        pk[1] = bf16_bits(avv[1] * inv);
        pk[2] = bf16_bits(avv[2] * inv);
        pk[3] = bf16_bits(avv[3] * inv);
        *reinterpret_cast<u16x4*>(
            attn_u + ((size_t)jc * kB + b_) * kE + h * kEh + c * 4) = pk;
        if (j >= 1) {
          nt_store4(av_out + ((size_t)b * (kN - 1) + (jc - 1)) * kEh + c * 4, avv);
          if (c == 0) a_sum_out[(size_t)b * (kN - 1) + (jc - 1)] = asum;
        }
      }
    }
    return;
  }

  // ---------------- ktv path ----------------
  int id2 = bid - 8192;
  int b = id2 >> 1, chunk = id2 & 1;

  if (tid < 64) qs[tid] = q_step[b * kEh + tid];
  __syncthreads();

  // phase 1: k_t shift + a_tb1 slice
  int c4 = chunk * 1024 + tid * 4;      // 0..2044 step 4
  bool last = (c4 + 4 >= kN);           // c4 == 2044 (chunk 1, tid 255)
  const float* src = k_t_mem + (size_t)b * kEh * kN;
  float* dst = k_t_out + (size_t)b * kEh * kN;

  f32x4 dot = {0.f, 0.f, 0.f, 0.f};
#pragma unroll 4
  for (int e = 0; e < 64; ++e) {
    f32x4 a = nt_load4(src + (size_t)e * kN + c4);
    float s3 = last ? 0.f
                    : __builtin_nontemporal_load(src + (size_t)e * kN + c4 + 4);
    f32x4 sh;
    sh[0] = a[1]; sh[1] = a[2]; sh[2] = a[3]; sh[3] = s3;
    nt_store4(dst + (size_t)e * kN + c4, sh);
    float q = qs[e];
    dot[0] += q * sh[0];
    dot[1] += q * sh[1];
    dot[2] += q * sh[2];
    dot[3] += q * sh[3];
  }
  float tx = __expf(dot[0]);
  float ty = __expf(dot[1]);
  float tz = __expf(dot[2]);
  float tw = last ? 0.f : __expf(dot[3]);  // col 2047 is not a valid slot

  tbuf[tid * 4 + 0] = tx;
  tbuf[tid * 4 + 1] = ty;
  tbuf[tid * 4 + 2] = tz;
  tbuf[tid * 4 + 3] = tw;

  float s = tx + ty + tz + tw;
  for (int off = 32; off > 0; off >>= 1) s += __shfl_xor(s, off, 64);
  if (lane == 0) redt[wave] = s;
  __syncthreads();  // publishes tbuf + redt
  if (tid == 0)
    atomicAdd(&top_sum[b], redt[0] + redt[1] + redt[2] + redt[3]);

  // phase 2: v shift + av_last accumulate over the same index range
  int g = lane >> 4, c = lane & 15;
  const float* vsrc = v_mem + (size_t)b * kN * kEh;
  float* vdst = v_out + (size_t)b * kN * kEh;

  f32x4 acc = {0.f, 0.f, 0.f, 0.f};
  int sbase = chunk * 1024 + wave * 256;
#pragma unroll 4
  for (int it = 0; it < 64; ++it) {
    int s4 = sbase + it * 4 + g;
    bool valid = (s4 <= kN - 2);         // only s==2047 masked
    int sc = valid ? s4 : (kN - 2);
    float t = valid ? tbuf[s4 - chunk * 1024] : 0.f;
    f32x4 vv = nt_load4(vsrc + (size_t)(sc + 1) * kEh + c * 4);
    acc[0] += t * vv[0];
    acc[1] += t * vv[1];
    acc[2] += t * vv[2];
    acc[3] += t * vv[3];
    if (valid) nt_store4(vdst + (size_t)sc * kEh + c * 4, vv);
  }
#pragma unroll
  for (int off = 16; off <= 32; off <<= 1) {
    acc[0] += __shfl_xor(acc[0], off, 64);
    acc[1] += __shfl_xor(acc[1], off, 64);
    acc[2] += __shfl_xor(acc[2], off, 64);
    acc[3] += __shfl_xor(acc[3], off, 64);
  }
  if (g == 0) redv[wave][c] = acc;
  __syncthreads();
  if (tid < 16) {
    f32x4 a0 = redv[0][tid];
    f32x4 a1 = redv[1][tid];
    f32x4 a2 = redv[2][tid];
    f32x4 a3 = redv[3][tid];
    float* dstl = av_last + (size_t)b * kEh + tid * 4;
    atomicAdd(dstl + 0, a0[0] + a1[0] + a2[0] + a3[0]);
    atomicAdd(dstl + 1, a0[1] + a1[1] + a2[1] + a3[1]);
    atomicAdd(dstl + 2, a0[2] + a1[2] + a2[2] + a3[2]);
    atomicAdd(dstl + 3, a0[3] + a1[3] + a2[3] + a3[3]);
  }
}

// ---------------------------------------------------------------------------
// Kernel 3: finalize. Last row/column of all states + attn last row.
// grid kBH, block 64. (unchanged)
// ---------------------------------------------------------------------------
__global__ __launch_bounds__(64) void final_kernel(
    const float* __restrict__ q_step, const float* __restrict__ k_step,
    const float* __restrict__ v_step, const float* __restrict__ top_sum,
    const float* __restrict__ av_last_in, float* __restrict__ q_out,
    float* __restrict__ k_t_out, float* __restrict__ v_out,
    float* __restrict__ a_sum_out, float* __restrict__ av_out,
    __hip_bfloat16* __restrict__ attn) {
  int b = blockIdx.x;
  int lane = threadIdx.x;
  int b_ = b >> 4, h = b & 15;
  float qs = q_step[b * kEh + lane];
  float ks = k_step[b * kEh + lane];
  float vs = v_step[b * kEh + lane];
  float p = qs * ks;
  for (int off = 32; off > 0; off >>= 1) p += __shfl_xor(p, off, 64);
  float abr = __expf(p);
  float asum = top_sum[b] + abr;
  float avl = av_last_in[b * kEh + lane] + abr * vs;
  attn[((size_t)(kN - 1) * kB + b_) * kE + h * kEh + lane] =
      __float2bfloat16(avl / asum);
  if (lane == 0) a_sum_out[(size_t)b * (kN - 1) + (kN - 2)] = asum;
  av_out[((size_t)b * (kN - 1) + (kN - 2)) * kEh + lane] = avl;
  q_out[((size_t)b * kN + (kN - 1)) * kEh + lane] = qs;
  k_t_out[(size_t)b * kEh * kN + (size_t)lane * kN + (kN - 1)] = ks;
  v_out[((size_t)b * kN + (kN - 1)) * kEh + lane] = vs;
}

// ---------------------------------------------------------------------------
// Kernel 4: out-projection GEMM, 256x256 tile, BK=64, 8 waves (512 thr),
// double-buffered 128 KiB LDS, counted vmcnt(8) pipeline (loads stay in
// flight across barriers - no drain), raw s_barrier, XCD-swizzled grid.
// C(32768 x 1024) = A(bf16) * W^T + bias.
// ---------------------------------------------------------------------------
#define GBM 256
#define GBN 256
#define GBK 64
#define GKT (kE / GBK)   // 16 K-tiles

__global__ __launch_bounds__(512, 2) void gemm_kernel(
    const __bf16* __restrict__ A, const __bf16* __restrict__ Bw,
    const float* __restrict__ bias, float* __restrict__ C) {
  // 2 buffers x (A,B) x 256 rows x 64 cols bf16 = 128 KiB
  __shared__ __bf16 lds[2][2][GBM * GBK];

  int tid = threadIdx.x;
  int wid = tid >> 6;
  int lane = tid & 63;

  // XCD-aware bijective swizzle (512 blocks, 512 % 8 == 0)
  int bid = blockIdx.x;
  int swz = (bid & 7) * 64 + (bid >> 3);
  int mt = swz >> 2;           // 0..127
  int nt = swz & 3;            // 0..3
  int m0 = mt * GBM;
  int n0 = nt * GBN;

  int wm = (wid >> 2) * 128;   // 0 or 128
  int wn = (wid & 3) * 64;     // 0,64,128,192

  int quad = lane >> 4;        // k sub-offset = quad*8
  int mrow = lane & 15;

  f32x4 acc[8][4];
#pragma unroll
  for (int i = 0; i < 8; ++i)
#pragma unroll
    for (int j = 0; j < 4; ++j) acc[i][j] = (f32x4){0.f, 0.f, 0.f, 0.f};

  // staging geometry: per issue, 512 threads x 16 B = 8 KiB = 64 rows x 128 B
  int srow = tid >> 3;             // 0..63
  int scol = (tid & 7) * 8;        // element offset within row: 0..56
  const __bf16* gA = A + (size_t)(m0 + srow) * kE + scol;
  const __bf16* gB = Bw + (size_t)(n0 + srow) * kE + scol;

  auto stage = [&](int t) {
    int buf = t & 1;
    int k0 = t * GBK;
#pragma unroll
    for (int q = 0; q < 4; ++q) {
      __builtin_amdgcn_global_load_lds(
          (const __attribute__((address_space(1))) void*)(gA + (size_t)q * 64 * kE + k0),
          (__attribute__((address_space(3))) void*)((char*)&lds[buf][0][0] + q * 8192 + tid * 16),
          16, 0, 0);
      __builtin_amdgcn_global_load_lds(
          (const __attribute__((address_space(1))) void*)(gB + (size_t)q * 64 * kE + k0),
          (__attribute__((address_space(3))) void*)((char*)&lds[buf][1][0] + q * 8192 + tid * 16),
          16, 0, 0);
    }
  };

  stage(0);                        // 8 loads in flight

  for (int t = 0; t < GKT; ++t) {
    if (t + 1 < GKT) stage(t + 1); // prefetch next tile into other buffer
    // wait for tile t (oldest 8 loads); keep tile t+1's 8 in flight
    if (t + 1 < GKT) {
      asm volatile("s_waitcnt vmcnt(8)" ::: "memory");
    } else {
      asm volatile("s_waitcnt vmcnt(0)" ::: "memory");
    }
    __builtin_amdgcn_s_barrier();  // all waves' tile-t data visible

    const __bf16* la = &lds[t & 1][0][0];
    const __bf16* lb = &lds[t & 1][1][0];
#pragma unroll
    for (int kk = 0; kk < 2; ++kk) {
      bf16x8 bfr[4];
#pragma unroll
      for (int j = 0; j < 4; ++j)
        bfr[j] = *(const bf16x8*)(lb + (wn + j * 16 + mrow) * GBK + kk * 32 + quad * 8);
#pragma unroll
      for (int i = 0; i < 8; ++i) {
        bf16x8 af = *(const bf16x8*)(la + (wm + i * 16 + mrow) * GBK + kk * 32 + quad * 8);
#pragma unroll
        for (int j = 0; j < 4; ++j)
          acc[i][j] = __builtin_amdgcn_mfma_f32_16x16x32_bf16(af, bfr[j], acc[i][j], 0, 0, 0);
      }
    }
    __builtin_amdgcn_s_barrier();  // protect buf reuse by next prefetch
  }

  // epilogue: C/D layout col=lane&15, row=(lane>>4)*4+reg
  int colq = lane & 15;
  int rowq = (lane >> 4) * 4;
#pragma unroll
  for (int i = 0; i < 8; ++i) {
#pragma unroll
    for (int j = 0; j < 4; ++j) {
      int col = n0 + wn + j * 16 + colq;
      float bv = bias[col];
      size_t base = (size_t)(m0 + wm + i * 16 + rowq) * kE + col;
#pragma unroll
      for (int r = 0; r < 4; ++r) {
        __builtin_nontemporal_store(acc[i][j][r] + bv, &C[base + (size_t)r * kE]);
      }
    }
  }
}

// ---------------------------------------------------------------------------
// Launch
// ---------------------------------------------------------------------------
extern "C" void kernel_launch(void* const* d_in, const int* in_sizes, int n_in,
                              void* d_out, int out_size, void* d_ws,
                              size_t ws_size, hipStream_t stream) {
  const float* query          = (const float*)d_in[0];
  const float* key_in         = (const float*)d_in[1];
  const float* value          = (const float*)d_in[2];
  const float* a_sum_mem      = (const float*)d_in[3];
  const float* av_mem         = (const float*)d_in[4];
  const float* q_mem          = (const float*)d_in[5];
  const float* k_t_mem        = (const float*)d_in[6];
  const float* v_mem          = (const float*)d_in[7];
  const float* in_proj_weight = (const float*)d_in[8];
  const float* in_proj_bias   = (const float*)d_in[9];
  const float* out_proj_weight= (const float*)d_in[10];
  const float* out_proj_bias  = (const float*)d_in[11];

  // Output layout (flat fp32, return order)
  float* out       = (float*)d_out;                          // N*B*E
  float* a_sum_out = out + (size_t)kN * kB * kE;             // BH*(N-1)
  float* av_out    = a_sum_out + (size_t)kBH * (kN - 1);     // BH*(N-1)*Eh
  float* q_out     = av_out + (size_t)kBH * (kN - 1) * kEh;  // BH*N*Eh
  float* k_t_out   = q_out + (size_t)kBH * kN * kEh;         // BH*Eh*N
  float* v_out     = k_t_out + (size_t)kBH * kEh * kN;       // BH*N*Eh

  // Workspace layout
  char* ws = (char*)d_ws;
  float* q_step  = (float*)ws;              // 16384 f
  float* k_step  = q_step + 16384;          // 16384 f
  float* v_step  = k_step + 16384;          // 16384 f
  float* top_sum = v_step + 16384;          // 256 f   (zeroed)
  float* av_last = top_sum + 256;           // 16384 f (zeroed)
  __hip_bfloat16* wo_bf   = (__hip_bfloat16*)(ws + 2359296);  // 1M bf16
  __hip_bfloat16* attn_bf = (__hip_bfloat16*)(ws + 4456448);  // 32M bf16

  // zero the atomic accumulators (top_sum + av_last = 16640 floats)
  hipMemsetAsync(ws + 196608, 0, 66560, stream);

  prep_kernel<<<4096, 256, 0, stream>>>(query, key_in, value, in_proj_weight,
                                        in_proj_bias, q_step, k_step, v_step,
                                        out_proj_weight, wo_bf);
  stream_kernel<<<8704, 256, 0, stream>>>(q_mem, av_mem, a_sum_mem, k_t_mem,
                                          v_mem, q_step, k_step, v_step, q_out,
                                          av_out, a_sum_out, k_t_out, v_out,
                                          top_sum, av_last, attn_bf);
  final_kernel<<<kBH, 64, 0, stream>>>(q_step, k_step, v_step, top_sum,
                                       av_last, q_out, k_t_out, v_out,
                                       a_sum_out, av_out, attn_bf);
  gemm_kernel<<<(kM / GBM) * (kE / GBN), 512, 0, stream>>>(
      (const __bf16*)attn_bf, (const __bf16*)wo_bf, out_proj_bias, out);
}

// Round 4
// 1107.729 us; speedup vs baseline: 1.0853x; 1.0059x over previous
//
#include <hip/hip_runtime.h>
#include <hip/hip_bf16.h>

// Problem constants
constexpr int kB  = 16;
constexpr int kE  = 1024;
constexpr int kH  = 16;
constexpr int kN  = 2048;
constexpr int kEh = 64;
constexpr int kBH = 256;
constexpr int kM  = kN * kB;   // 32768 rows in the out-projection GEMM

typedef __bf16 bf16x8 __attribute__((ext_vector_type(8)));
typedef float  f32x4  __attribute__((ext_vector_type(4)));
typedef unsigned short u16x4 __attribute__((ext_vector_type(4)));

static __device__ __forceinline__ unsigned short bf16_bits(float f) {
  union { __hip_bfloat16 h; unsigned short u; } cv;
  cv.h = __float2bfloat16(f);
  return cv.u;
}

static __device__ __forceinline__ f32x4 nt_load4(const float* p) {
  return __builtin_nontemporal_load(reinterpret_cast<const f32x4*>(p));
}
static __device__ __forceinline__ void nt_store4(float* p, f32x4 v) {
  __builtin_nontemporal_store(v, reinterpret_cast<f32x4*>(p));
}

// ---------------------------------------------------------------------------
// Kernel 1: prep = in-projection (blocks 0..3071) + W_out fp32->bf16 cvt
// (blocks 3072..4095) + accumulator zeroing (blocks 4096..4160, replaces
// the hipMemsetAsync dispatch).
// ---------------------------------------------------------------------------
__global__ __launch_bounds__(256) void prep_kernel(
    const float* __restrict__ query, const float* __restrict__ key_in,
    const float* __restrict__ value, const float* __restrict__ W,
    const float* __restrict__ bias,
    float* __restrict__ q_step, float* __restrict__ k_step,
    float* __restrict__ v_step,
    const float* __restrict__ wo, __hip_bfloat16* __restrict__ wo_bf,
    float* __restrict__ zero_base) {
  __shared__ float red[4][16];
  int bid = blockIdx.x;
  int tid = threadIdx.x;
  if (bid >= 4096) {
    // ---- zero top_sum + av_last: 65 blocks x 256 = 16640 floats ----
    zero_base[(bid - 4096) * 256 + tid] = 0.f;
    return;
  }
  if (bid >= 3072) {
    // ---- weight conversion: 1024 blocks x 256 threads x 4 elems ----
    int i4 = ((bid - 3072) * 256 + tid) * 4;
    f32x4 w4 = nt_load4(wo + i4);
    u16x4 o;
    o[0] = bf16_bits(w4[0]); o[1] = bf16_bits(w4[1]);
    o[2] = bf16_bits(w4[2]); o[3] = bf16_bits(w4[3]);
    *reinterpret_cast<u16x4*>(reinterpret_cast<unsigned short*>(wo_bf) + i4) = o;
    return;
  }
  // ---- in-projection ----
  int j   = bid;               // 0..3071
  int mat = j >> 10;           // 0=q,1=k,2=v
  int col = j & 1023;
  const float* in = (mat == 0) ? query : ((mat == 1) ? key_in : value);
  const float* wrow = W + (size_t)j * kE;

  float4 w4 = reinterpret_cast<const float4*>(wrow)[tid];
  float part[16];
#pragma unroll
  for (int r = 0; r < 16; ++r) {
    float4 in4 = reinterpret_cast<const float4*>(in + (size_t)r * kE)[tid];
    part[r] = w4.x * in4.x + w4.y * in4.y + w4.z * in4.z + w4.w * in4.w;
  }
#pragma unroll
  for (int r = 0; r < 16; ++r) {
    float v = part[r];
    for (int off = 32; off > 0; off >>= 1) v += __shfl_down(v, off, 64);
    part[r] = v;
  }
  int wave = tid >> 6;
  int lane = tid & 63;
  if (lane == 0) {
#pragma unroll
    for (int r = 0; r < 16; ++r) red[wave][r] = part[r];
  }
  __syncthreads();
  if (tid < 16) {
    int r = tid;  // batch row
    float v = red[0][r] + red[1][r] + red[2][r] + red[3][r] + bias[j];
    int h = col >> 6, eh = col & 63;
    int bh = r * kH + h;
    if (mat == 0)      q_step[bh * kEh + eh] = v * 0.125f;  // 1/sqrt(64)
    else if (mat == 1) k_step[bh * kEh + eh] = v;
    else               v_step[bh * kEh + eh] = v;
  }
}

// ---------------------------------------------------------------------------
// Kernel 2: stream = qav (blocks 0..8191) + fused kt/v (blocks 8192..8703).
// (unchanged from verified R2/R3 version)
// ---------------------------------------------------------------------------
__global__ __launch_bounds__(256) void stream_kernel(
    const float* __restrict__ q_mem, const float* __restrict__ av_mem,
    const float* __restrict__ a_sum_mem, const float* __restrict__ k_t_mem,
    const float* __restrict__ v_mem, const float* __restrict__ q_step,
    const float* __restrict__ k_step, const float* __restrict__ v_step,
    float* __restrict__ q_out, float* __restrict__ av_out,
    float* __restrict__ a_sum_out, float* __restrict__ k_t_out,
    float* __restrict__ v_out, float* __restrict__ top_sum,
    float* __restrict__ av_last, __hip_bfloat16* __restrict__ attn) {
  __shared__ float qs[64];
  __shared__ float tbuf[1024];
  __shared__ f32x4 redv[4][16];
  __shared__ float redt[4];

  int bid = blockIdx.x;
  int tid = threadIdx.x;
  int wave = tid >> 6, lane = tid & 63;

  if (bid < 8192) {
    // ---------------- qav path ----------------
    int b = bid >> 5;
    int chunk = bid & 31;
    int g = lane >> 4, c = lane & 15;
    int b_ = b >> 4, h = b & 15;

    f32x4 kst  = *reinterpret_cast<const f32x4*>(k_step + (size_t)b * kEh + c * 4);
    f32x4 vst  = *reinterpret_cast<const f32x4*>(v_step + (size_t)b * kEh + c * 4);
    f32x4 vold = *reinterpret_cast<const f32x4*>(v_mem + (size_t)b * kN * kEh + c * 4);
    const float* kt0 = k_t_mem + (size_t)b * kEh * kN;
    f32x4 kold;
    kold[0] = kt0[(size_t)(4 * c + 0) * kN];
    kold[1] = kt0[(size_t)(4 * c + 1) * kN];
    kold[2] = kt0[(size_t)(4 * c + 2) * kN];
    kold[3] = kt0[(size_t)(4 * c + 3) * kN];

    unsigned short* attn_u = reinterpret_cast<unsigned short*>(attn);

    int jb = chunk * 64 + wave * 16;
#pragma unroll
    for (int it = 0; it < 4; ++it) {
      int j = jb + it * 4 + g;
      bool valid = (j <= kN - 2);        // only j==2047 masked
      int jc = valid ? j : (kN - 2);

      f32x4 q4 = nt_load4(q_mem + ((size_t)b * kN + (jc + 1)) * kEh + c * 4);
      float p0 = q4[0] * kold[0] + q4[1] * kold[1] + q4[2] * kold[2] + q4[3] * kold[3];
      float p1 = q4[0] * kst[0]  + q4[1] * kst[1]  + q4[2] * kst[2]  + q4[3] * kst[3];
#pragma unroll
      for (int off = 1; off < 16; off <<= 1) {
        p0 += __shfl_xor(p0, off, 64);
        p1 += __shfl_xor(p1, off, 64);
      }
      float a0 = __expf(p0);
      float a1 = __expf(p1);
      float asum = a_sum_mem[(size_t)b * (kN - 1) + jc] + a1 - a0;
      f32x4 av4 = nt_load4(av_mem + ((size_t)b * (kN - 1) + jc) * kEh + c * 4);
      f32x4 avv;
      avv[0] = av4[0] - a0 * vold[0] + a1 * vst[0];
      avv[1] = av4[1] - a0 * vold[1] + a1 * vst[1];
      avv[2] = av4[2] - a0 * vold[2] + a1 * vst[2];
      avv[3] = av4[3] - a0 * vold[3] + a1 * vst[3];

      if (valid) {
        nt_store4(q_out + ((size_t)b * kN + jc) * kEh + c * 4, q4);
        float inv = 1.0f / asum;
        u16x4 pk;
        pk[0] = bf16_bits(avv[0] * inv);
        pk[1] = bf16_bits(avv[1] * inv);
        pk[2] = bf16_bits(avv[2] * inv);
        pk[3] = bf16_bits(avv[3] * inv);
        *reinterpret_cast<u16x4*>(
            attn_u + ((size_t)jc * kB + b_) * kE + h * kEh + c * 4) = pk;
        if (j >= 1) {
          nt_store4(av_out + ((size_t)b * (kN - 1) + (jc - 1)) * kEh + c * 4, avv);
          if (c == 0) a_sum_out[(size_t)b * (kN - 1) + (jc - 1)] = asum;
        }
      }
    }
    return;
  }

  // ---------------- ktv path ----------------
  int id2 = bid - 8192;
  int b = id2 >> 1, chunk = id2 & 1;

  if (tid < 64) qs[tid] = q_step[b * kEh + tid];
  __syncthreads();

  // phase 1: k_t shift + a_tb1 slice
  int c4 = chunk * 1024 + tid * 4;      // 0..2044 step 4
  bool last = (c4 + 4 >= kN);           // c4 == 2044 (chunk 1, tid 255)
  const float* src = k_t_mem + (size_t)b * kEh * kN;
  float* dst = k_t_out + (size_t)b * kEh * kN;

  f32x4 dot = {0.f, 0.f, 0.f, 0.f};
#pragma unroll 4
  for (int e = 0; e < 64; ++e) {
    f32x4 a = nt_load4(src + (size_t)e * kN + c4);
    float s3 = last ? 0.f
                    : __builtin_nontemporal_load(src + (size_t)e * kN + c4 + 4);
    f32x4 sh;
    sh[0] = a[1]; sh[1] = a[2]; sh[2] = a[3]; sh[3] = s3;
    nt_store4(dst + (size_t)e * kN + c4, sh);
    float q = qs[e];
    dot[0] += q * sh[0];
    dot[1] += q * sh[1];
    dot[2] += q * sh[2];
    dot[3] += q * sh[3];
  }
  float tx = __expf(dot[0]);
  float ty = __expf(dot[1]);
  float tz = __expf(dot[2]);
  float tw = last ? 0.f : __expf(dot[3]);  // col 2047 is not a valid slot

  tbuf[tid * 4 + 0] = tx;
  tbuf[tid * 4 + 1] = ty;
  tbuf[tid * 4 + 2] = tz;
  tbuf[tid * 4 + 3] = tw;

  float s = tx + ty + tz + tw;
  for (int off = 32; off > 0; off >>= 1) s += __shfl_xor(s, off, 64);
  if (lane == 0) redt[wave] = s;
  __syncthreads();  // publishes tbuf + redt
  if (tid == 0)
    atomicAdd(&top_sum[b], redt[0] + redt[1] + redt[2] + redt[3]);

  // phase 2: v shift + av_last accumulate over the same index range
  int g = lane >> 4, c = lane & 15;
  const float* vsrc = v_mem + (size_t)b * kN * kEh;
  float* vdst = v_out + (size_t)b * kN * kEh;

  f32x4 acc = {0.f, 0.f, 0.f, 0.f};
  int sbase = chunk * 1024 + wave * 256;
#pragma unroll 4
  for (int it = 0; it < 64; ++it) {
    int s4 = sbase + it * 4 + g;
    bool valid = (s4 <= kN - 2);         // only s==2047 masked
    int sc = valid ? s4 : (kN - 2);
    float t = valid ? tbuf[s4 - chunk * 1024] : 0.f;
    f32x4 vv = nt_load4(vsrc + (size_t)(sc + 1) * kEh + c * 4);
    acc[0] += t * vv[0];
    acc[1] += t * vv[1];
    acc[2] += t * vv[2];
    acc[3] += t * vv[3];
    if (valid) nt_store4(vdst + (size_t)sc * kEh + c * 4, vv);
  }
#pragma unroll
  for (int off = 16; off <= 32; off <<= 1) {
    acc[0] += __shfl_xor(acc[0], off, 64);
    acc[1] += __shfl_xor(acc[1], off, 64);
    acc[2] += __shfl_xor(acc[2], off, 64);
    acc[3] += __shfl_xor(acc[3], off, 64);
  }
  if (g == 0) redv[wave][c] = acc;
  __syncthreads();
  if (tid < 16) {
    f32x4 a0 = redv[0][tid];
    f32x4 a1 = redv[1][tid];
    f32x4 a2 = redv[2][tid];
    f32x4 a3 = redv[3][tid];
    float* dstl = av_last + (size_t)b * kEh + tid * 4;
    atomicAdd(dstl + 0, a0[0] + a1[0] + a2[0] + a3[0]);
    atomicAdd(dstl + 1, a0[1] + a1[1] + a2[1] + a3[1]);
    atomicAdd(dstl + 2, a0[2] + a1[2] + a2[2] + a3[2]);
    atomicAdd(dstl + 3, a0[3] + a1[3] + a2[3] + a3[3]);
  }
}

// ---------------------------------------------------------------------------
// Kernel 3: finalize. Last row/column of all states + attn last row.
// grid kBH, block 64. (unchanged)
// ---------------------------------------------------------------------------
__global__ __launch_bounds__(64) void final_kernel(
    const float* __restrict__ q_step, const float* __restrict__ k_step,
    const float* __restrict__ v_step, const float* __restrict__ top_sum,
    const float* __restrict__ av_last_in, float* __restrict__ q_out,
    float* __restrict__ k_t_out, float* __restrict__ v_out,
    float* __restrict__ a_sum_out, float* __restrict__ av_out,
    __hip_bfloat16* __restrict__ attn) {
  int b = blockIdx.x;
  int lane = threadIdx.x;
  int b_ = b >> 4, h = b & 15;
  float qs = q_step[b * kEh + lane];
  float ks = k_step[b * kEh + lane];
  float vs = v_step[b * kEh + lane];
  float p = qs * ks;
  for (int off = 32; off > 0; off >>= 1) p += __shfl_xor(p, off, 64);
  float abr = __expf(p);
  float asum = top_sum[b] + abr;
  float avl = av_last_in[b * kEh + lane] + abr * vs;
  attn[((size_t)(kN - 1) * kB + b_) * kE + h * kEh + lane] =
      __float2bfloat16(avl / asum);
  if (lane == 0) a_sum_out[(size_t)b * (kN - 1) + (kN - 2)] = asum;
  av_out[((size_t)b * (kN - 1) + (kN - 2)) * kEh + lane] = avl;
  q_out[((size_t)b * kN + (kN - 1)) * kEh + lane] = qs;
  k_t_out[(size_t)b * kEh * kN + (size_t)lane * kN + (kN - 1)] = ks;
  v_out[((size_t)b * kN + (kN - 1)) * kEh + lane] = vs;
}

// ---------------------------------------------------------------------------
// Kernel 4: out-projection GEMM, 256x256 tile, BK=64, 8 waves (512 thr),
// double-buffered 128 KiB LDS, counted vmcnt(8) pipeline, XCD-swizzled grid.
// NEW: epilogue re-stages C through LDS (32x260-padded f32 tile) so the
// 134 MB C write goes out as coalesced 16 B/lane dwordx4 NT stores instead
// of scalar dwords at 4 KB stride.
// ---------------------------------------------------------------------------
#define GBM 256
#define GBN 256
#define GBK 64
#define GKT (kE / GBK)   // 16 K-tiles

__global__ __launch_bounds__(512, 2) void gemm_kernel(
    const __bf16* __restrict__ A, const __bf16* __restrict__ Bw,
    const float* __restrict__ bias, float* __restrict__ C) {
  // 2 buffers x (A,B) x 256 rows x 64 cols bf16 = 128 KiB
  __shared__ __bf16 lds[2][2][GBM * GBK];

  int tid = threadIdx.x;
  int wid = tid >> 6;
  int lane = tid & 63;

  // XCD-aware bijective swizzle (512 blocks, 512 % 8 == 0).
  // Note: the 4 N-tiles sharing one A M-panel get identical bid%8 -> same
  // XCD -> A panel is L2-reused (read ~once from HBM).
  int bid = blockIdx.x;
  int swz = (bid & 7) * 64 + (bid >> 3);
  int mt = swz >> 2;           // 0..127
  int nt = swz & 3;            // 0..3
  int m0 = mt * GBM;
  int n0 = nt * GBN;

  int wm = (wid >> 2) * 128;   // 0 or 128
  int wn = (wid & 3) * 64;     // 0,64,128,192

  int quad = lane >> 4;        // k sub-offset = quad*8
  int mrow = lane & 15;

  f32x4 acc[8][4];
#pragma unroll
  for (int i = 0; i < 8; ++i)
#pragma unroll
    for (int j = 0; j < 4; ++j) acc[i][j] = (f32x4){0.f, 0.f, 0.f, 0.f};

  // staging geometry: per issue, 512 threads x 16 B = 8 KiB = 64 rows x 128 B
  int srow = tid >> 3;             // 0..63
  int scol = (tid & 7) * 8;        // element offset within row: 0..56
  const __bf16* gA = A + (size_t)(m0 + srow) * kE + scol;
  const __bf16* gB = Bw + (size_t)(n0 + srow) * kE + scol;

  auto stage = [&](int t) {
    int buf = t & 1;
    int k0 = t * GBK;
#pragma unroll
    for (int q = 0; q < 4; ++q) {
      __builtin_amdgcn_global_load_lds(
          (const __attribute__((address_space(1))) void*)(gA + (size_t)q * 64 * kE + k0),
          (__attribute__((address_space(3))) void*)((char*)&lds[buf][0][0] + q * 8192 + tid * 16),
          16, 0, 0);
      __builtin_amdgcn_global_load_lds(
          (const __attribute__((address_space(1))) void*)(gB + (size_t)q * 64 * kE + k0),
          (__attribute__((address_space(3))) void*)((char*)&lds[buf][1][0] + q * 8192 + tid * 16),
          16, 0, 0);
    }
  };

  stage(0);                        // 8 loads in flight

  for (int t = 0; t < GKT; ++t) {
    if (t + 1 < GKT) stage(t + 1); // prefetch next tile into other buffer
    // wait for tile t (oldest 8 loads); keep tile t+1's 8 in flight
    if (t + 1 < GKT) {
      asm volatile("s_waitcnt vmcnt(8)" ::: "memory");
    } else {
      asm volatile("s_waitcnt vmcnt(0)" ::: "memory");
    }
    __builtin_amdgcn_s_barrier();  // all waves' tile-t data visible

    const __bf16* la = &lds[t & 1][0][0];
    const __bf16* lb = &lds[t & 1][1][0];
#pragma unroll
    for (int kk = 0; kk < 2; ++kk) {
      bf16x8 bfr[4];
#pragma unroll
      for (int j = 0; j < 4; ++j)
        bfr[j] = *(const bf16x8*)(lb + (wn + j * 16 + mrow) * GBK + kk * 32 + quad * 8);
#pragma unroll
      for (int i = 0; i < 8; ++i) {
        bf16x8 af = *(const bf16x8*)(la + (wm + i * 16 + mrow) * GBK + kk * 32 + quad * 8);
#pragma unroll
        for (int j = 0; j < 4; ++j)
          acc[i][j] = __builtin_amdgcn_mfma_f32_16x16x32_bf16(af, bfr[j], acc[i][j], 0, 0, 0);
      }
    }
    __builtin_amdgcn_s_barrier();  // protect buf reuse by next prefetch
  }

  // ---- epilogue: LDS-staged coalesced C stores ----
  // C/D layout: col = lane&15, row = (lane>>4)*4 + reg.
  float* cst = reinterpret_cast<float*>(&lds[0][0][0]);  // 32 x 260 f32 (33 KB)
  int colq = lane & 15;
  int rowq = lane >> 4;            // 0..3
  float bv[4];
#pragma unroll
  for (int j = 0; j < 4; ++j) bv[j] = bias[n0 + wn + j * 16 + colq];

  int lrow_base = (wm >> 7) * 16 + rowq * 4;  // wm=0 -> 0..15, wm=128 -> 16..31
  int r_t = tid >> 4;              // 0..31 (LDS row this thread stores)
  int c4 = (tid & 15) * 4;         // f32 col base within 64-col group
  int grow = m0 + (r_t >> 4) * 128 + (r_t & 15);  // + i*16 in loop

#pragma unroll
  for (int i = 0; i < 8; ++i) {
    __syncthreads();               // prior LDS use (main loop / prev reads) done
#pragma unroll
    for (int j = 0; j < 4; ++j) {
      int cw = wn + j * 16 + colq;
#pragma unroll
      for (int r = 0; r < 4; ++r)
        cst[(lrow_base + r) * 260 + cw] = acc[i][j][r] + bv[j];
    }
    __syncthreads();               // tile i fully staged
    size_t gbase = (size_t)(grow + i * 16) * kE + n0 + c4;
#pragma unroll
    for (int k4 = 0; k4 < 4; ++k4) {
      f32x4 vv = *reinterpret_cast<const f32x4*>(&cst[r_t * 260 + c4 + k4 * 64]);
      __builtin_nontemporal_store(vv, reinterpret_cast<f32x4*>(&C[gbase + (size_t)k4 * 64]));
    }
  }
}

// ---------------------------------------------------------------------------
// Launch
// ---------------------------------------------------------------------------
extern "C" void kernel_launch(void* const* d_in, const int* in_sizes, int n_in,
                              void* d_out, int out_size, void* d_ws,
                              size_t ws_size, hipStream_t stream) {
  const float* query          = (const float*)d_in[0];
  const float* key_in         = (const float*)d_in[1];
  const float* value          = (const float*)d_in[2];
  const float* a_sum_mem      = (const float*)d_in[3];
  const float* av_mem         = (const float*)d_in[4];
  const float* q_mem          = (const float*)d_in[5];
  const float* k_t_mem        = (const float*)d_in[6];
  const float* v_mem          = (const float*)d_in[7];
  const float* in_proj_weight = (const float*)d_in[8];
  const float* in_proj_bias   = (const float*)d_in[9];
  const float* out_proj_weight= (const float*)d_in[10];
  const float* out_proj_bias  = (const float*)d_in[11];

  // Output layout (flat fp32, return order)
  float* out       = (float*)d_out;                          // N*B*E
  float* a_sum_out = out + (size_t)kN * kB * kE;             // BH*(N-1)
  float* av_out    = a_sum_out + (size_t)kBH * (kN - 1);     // BH*(N-1)*Eh
  float* q_out     = av_out + (size_t)kBH * (kN - 1) * kEh;  // BH*N*Eh
  float* k_t_out   = q_out + (size_t)kBH * kN * kEh;         // BH*Eh*N
  float* v_out     = k_t_out + (size_t)kBH * kEh * kN;       // BH*N*Eh

  // Workspace layout
  char* ws = (char*)d_ws;
  float* q_step  = (float*)ws;              // 16384 f
  float* k_step  = q_step + 16384;          // 16384 f
  float* v_step  = k_step + 16384;          // 16384 f
  float* top_sum = v_step + 16384;          // 256 f   (zeroed by prep)
  float* av_last = top_sum + 256;           // 16384 f (zeroed by prep)
  __hip_bfloat16* wo_bf   = (__hip_bfloat16*)(ws + 2359296);  // 1M bf16
  __hip_bfloat16* attn_bf = (__hip_bfloat16*)(ws + 4456448);  // 32M bf16

  // prep grid: 3072 proj + 1024 wcvt + 65 zeroing (16640 floats) = 4161
  prep_kernel<<<4161, 256, 0, stream>>>(query, key_in, value, in_proj_weight,
                                        in_proj_bias, q_step, k_step, v_step,
                                        out_proj_weight, wo_bf, top_sum);
  stream_kernel<<<8704, 256, 0, stream>>>(q_mem, av_mem, a_sum_mem, k_t_mem,
                                          v_mem, q_step, k_step, v_step, q_out,
                                          av_out, a_sum_out, k_t_out, v_out,
                                          top_sum, av_last, attn_bf);
  final_kernel<<<kBH, 64, 0, stream>>>(q_step, k_step, v_step, top_sum,
                                       av_last, q_out, k_t_out, v_out,
                                       a_sum_out, av_out, attn_bf);
  gemm_kernel<<<(kM / GBM) * (kE / GBN), 512, 0, stream>>>(
      (const __bf16*)attn_bf, (const __bf16*)wo_bf, out_proj_bias, out);
}